// Round 6
// baseline (294.403 us; speedup 1.0000x reference)
//
#include <hip/hip_runtime.h>

#define N 128
#define NN 16384            // N*N
#define M 2048
#define TILE_F4 256         // float4 per 4-KiB tile (8 rows)
#define TPS 16              // tiles per stream (64 KiB / 4 KiB)
#define TOT 32              // re + im

// ws layout (floats):
// [0..512)     E: float4 per column j: (e0r_j, e0i_j, e1r_j, e1i_j)
// [512..1024)  G: float4 per row  i: (l0*e0r_i, l0*e0i_i, l1*e1r_i, l1*e1i_i)

__device__ __forceinline__ void gl_lds16(const float4* g, float4* l) {
    __builtin_amdgcn_global_load_lds(
        (__attribute__((address_space(1))) void*)const_cast<float4*>(g),
        (__attribute__((address_space(3))) void*)l,
        16, 0, 0);
}

__device__ __forceinline__ float block_reduce128(float v, float* red, int i) {
    __syncthreads();
    red[i] = v;
    __syncthreads();
    for (int off = 64; off > 0; off >>= 1) {
        if (i < off) red[i] += red[i + off];
        __syncthreads();
    }
    return red[0];
}

__global__ void prep_kernel(const float* __restrict__ theta,
                            const float* __restrict__ evl,
                            float* __restrict__ ws) {
    __shared__ float red[N];
    const int i = threadIdx.x;   // 128 threads

    float c0r = theta[i], c0i = theta[N + i];
    float s0 = block_reduce128(c0r * c0r + c0i * c0i, red, i);
    float inv0 = rsqrtf(s0);
    float a0r = c0r * inv0, a0i = c0i * inv0;

    // c1 -= vdot(evc0, c1) * evc0   (vdot conjugates first arg)
    float c1r = theta[2 * N + i], c1i = theta[3 * N + i];
    float dr = block_reduce128(a0r * c1r + a0i * c1i, red, i);
    float di = block_reduce128(a0r * c1i - a0i * c1r, red, i);
    c1r -= dr * a0r - di * a0i;
    c1i -= dr * a0i + di * a0r;

    float s1 = block_reduce128(c1r * c1r + c1i * c1i, red, i);
    float inv1 = rsqrtf(s1);
    float a1r = c1r * inv1, a1i = c1i * inv1;

    float l0 = log1pf(expf(evl[0]));
    float l1 = log1pf(expf(evl[1]));
    float inl = rsqrtf(l0 * l0 + l1 * l1);
    l0 *= inl; l1 *= inl;

    float4* E4 = (float4*)ws;
    E4[i]       = make_float4(a0r, a0i, a1r, a1i);
    E4[128 + i] = make_float4(l0 * a0r, l0 * a0i, l1 * a1r, l1 * a1i);
}

// ---------------------------------------------------------------------------
// One block per k. Stream k's 128 KiB (re then im) through a 4-tile LDS ring
// staged by global_load_lds (16-B DMA, no VGPR round-trip). Rank-2 body:
//   Hr(i,j) = g0r_i*e0r_j + g0i_i*e0i_j - g1r_i*e1r_j - g1i_i*e1i_j
//   Hi(i,j) = g0i_i*e0r_j - g0r_i*e0i_j - g1i_i*e1r_j + g1r_i*e1i_j
// Per-lane column block fixed -> E in 16 registers. Block owns all of k:
// reduce in-block, one atomicAdd of |v_k|^2.
// ---------------------------------------------------------------------------
__global__ __launch_bounds__(256, 8) void dot_kernel(
        const float4* __restrict__ br, const float4* __restrict__ bi,
        const float* __restrict__ ws, float* __restrict__ out) {
    __shared__ __align__(16) float4 stage[4][TILE_F4];   // 16 KiB ring
    __shared__ __align__(16) float4 sG[N];               // 2 KiB row constants
    __shared__ float swr[4], swi[4];
    const int t = threadIdx.x;
    const int k = blockIdx.x;

    if (t < N) sG[t] = ((const float4*)ws)[N + t];

    const float4* E4 = (const float4*)ws;
    const int j4 = t & 31;                               // fixed column block
    float4 E0 = E4[4 * j4 + 0];
    float4 E1 = E4[4 * j4 + 1];
    float4 E2 = E4[4 * j4 + 2];
    float4 E3 = E4[4 * j4 + 3];

    const float4* srcR = br + (size_t)k * (NN / 4);
    const float4* srcI = bi + (size_t)k * (NN / 4);

    // prime the ring with tiles 0 and 1
    gl_lds16(srcR + 0 * TILE_F4 + t, &stage[0][t]);
    gl_lds16(srcR + 1 * TILE_F4 + t, &stage[1][t]);

    float Pr = 0.f, Qr = 0.f, Pi = 0.f, Qi = 0.f;
    for (int tt = 0; tt < TOT; ++tt) {
        if (tt < TOT - 2) {
            const int nt = tt + 2;
            const float4* s = (nt < TPS) ? (srcR + nt * TILE_F4)
                                         : (srcI + (nt - TPS) * TILE_F4);
            gl_lds16(s + t, &stage[nt & 3][t]);
        }
        __syncthreads();                                 // drain DMA, sync ring

        float4 a = stage[tt & 3][t];
        const int row = ((tt & 15) << 3) + (t >> 5);
        float4 g = sG[row];
        float d0r = a.x * E0.x + a.y * E1.x + a.z * E2.x + a.w * E3.x;
        float d0i = a.x * E0.y + a.y * E1.y + a.z * E2.y + a.w * E3.y;
        float d1r = a.x * E0.z + a.y * E1.z + a.z * E2.z + a.w * E3.z;
        float d1i = a.x * E0.w + a.y * E1.w + a.z * E2.w + a.w * E3.w;
        float dP = g.x * d0r + g.y * d0i - g.z * d1r - g.w * d1i;
        float dQ = g.y * d0r - g.x * d0i - g.w * d1r + g.z * d1i;
        if (tt < TPS) { Pr += dP; Qr += dQ; }
        else          { Pi += dP; Qi += dQ; }
    }

    // v_k = (Pr + Qi) + i(Qr - Pi); reduce across block, emit |v_k|^2
    float vr = Pr + Qi, vi = Qr - Pi;
    for (int off = 32; off > 0; off >>= 1) {
        vr += __shfl_down(vr, off);
        vi += __shfl_down(vi, off);
    }
    const int wave = t >> 6, lane = t & 63;
    if (lane == 0) { swr[wave] = vr; swi[wave] = vi; }
    __syncthreads();
    if (t == 0) {
        float R = swr[0] + swr[1] + swr[2] + swr[3];
        float I = swi[0] + swi[1] + swi[2] + swi[3];
        atomicAdd(out, R * R + I * I);
    }
}

extern "C" void kernel_launch(void* const* d_in, const int* in_sizes, int n_in,
                              void* d_out, int out_size, void* d_ws, size_t ws_size,
                              hipStream_t stream) {
    const float* basis_re = (const float*)d_in[0];
    const float* basis_im = (const float*)d_in[1];
    const float* theta    = (const float*)d_in[2];
    const float* evl      = (const float*)d_in[3];
    float* out = (float*)d_out;
    float* ws  = (float*)d_ws;

    hipMemsetAsync(d_out, 0, sizeof(float), stream);
    prep_kernel<<<1, 128, 0, stream>>>(theta, evl, ws);
    dot_kernel<<<M, 256, 0, stream>>>((const float4*)basis_re,
                                      (const float4*)basis_im,
                                      ws, out);
}